// Round 3
// baseline (384.521 us; speedup 1.0000x reference)
//
#include <hip/hip_runtime.h>
#include <math.h>

namespace {

constexpr int LNUM = 2097152;        // L
constexpr int NROW = 5;              // N
constexpr int NSER = 10;             // rows total (0..4 rppg, 5..9 ppg)
constexpr int TPB = 256;
constexpr int EPL = 16;              // elements per lane (one 64B line)
constexpr int CHUNK = TPB * EPL;     // 4096 per block
constexpr int CPR = LNUM / CHUNK;    // 512 chunks per row
constexpr int NBLK = NSER * CPR;     // 5120

struct Agg { int first; int last; int c; double s; };

__device__ __forceinline__ Agg combine(const Agg& a, const Agg& b) {
  // ordered segment-concat monoid: a LEFT, b RIGHT (non-commutative)
  Agg r;
  r.first = (a.first >= 0) ? a.first : b.first;
  r.last  = (b.last >= 0) ? b.last : a.last;
  r.s = a.s + b.s;
  r.c = a.c + b.c;
  if (a.last >= 0 && b.first >= 0) {
    r.s += 1.0 / (double)(b.first - a.last);
    r.c += 1;
  }
  return r;
}

// Per-lane: 16 contiguous elements at row-relative offset s (s % 16 == 0).
// Own data = exactly one 64B line via 4x dwordx4; halo +-5 via shuffles from
// neighbor lanes; lanes 0/63 patch halo with guarded global loads (-inf pad
// at row edges). Window-11 max via register doubling (m2/m4/m8).
// X[i] = x[s-5+i]  (i=0..25);  w[t] = max over window of center X[5+t].
__device__ __forceinline__ void window16(const float* __restrict__ x, int s,
                                         float X[26], float w[16]) {
  const float4* q = reinterpret_cast<const float4*>(x + s);
  float4 f0 = q[0], f1 = q[1], f2 = q[2], f3 = q[3];
  X[5] = f0.x;  X[6] = f0.y;  X[7] = f0.z;  X[8] = f0.w;
  X[9] = f1.x;  X[10] = f1.y; X[11] = f1.z; X[12] = f1.w;
  X[13] = f2.x; X[14] = f2.y; X[15] = f2.z; X[16] = f2.w;
  X[17] = f3.x; X[18] = f3.y; X[19] = f3.z; X[20] = f3.w;
#pragma unroll
  for (int j = 0; j < 5; ++j) X[j] = __shfl_up(X[16 + j], 1);      // x[s-5+j]
#pragma unroll
  for (int j = 0; j < 5; ++j) X[21 + j] = __shfl_down(X[5 + j], 1); // x[s+16+j]
  const int lane = threadIdx.x & 63;
  if (lane == 0) {
#pragma unroll
    for (int j = 0; j < 5; ++j) {
      int g = s - 5 + j;
      X[j] = (g >= 0) ? x[g] : -INFINITY;
    }
  }
  if (lane == 63) {
#pragma unroll
    for (int j = 0; j < 5; ++j) {
      int g = s + 16 + j;
      X[21 + j] = (g < LNUM) ? x[g] : -INFINITY;
    }
  }
  float m2[25];
#pragma unroll
  for (int i = 0; i < 25; ++i) m2[i] = fmaxf(X[i], X[i + 1]);
  float m4[23];
#pragma unroll
  for (int i = 0; i < 23; ++i) m4[i] = fmaxf(m2[i], m2[i + 2]);
  float m8[19];
#pragma unroll
  for (int i = 0; i < 19; ++i) m8[i] = fmaxf(m4[i], m4[i + 4]);
#pragma unroll
  for (int t = 0; t < 16; ++t) w[t] = fmaxf(m8[t], m8[t + 3]);  // X[t..t+10]
}

__device__ __forceinline__ const float* row_ptr(const float* rppg,
                                                const float* ppg, int rw) {
  return (rw < NROW) ? rppg + (size_t)rw * LNUM
                     : ppg + (size_t)(rw - NROW) * LNUM;
}

// Pass 1: per-chunk {sum, peak-value-sum, peak-count}; last block computes
// per-row raw-domain thresholds:  x_norm > mean_pk_norm/2  <=>
// x > (mu + mean_pk_raw)/2   (normalization is monotone affine, sd cancels).
__global__ __launch_bounds__(TPB) void stats_kernel(
    const float* __restrict__ rppg, const float* __restrict__ ppg,
    double* __restrict__ psum, double* __restrict__ ppk,
    int* __restrict__ pnpk, double* __restrict__ thr,
    int* __restrict__ counter) {
  const int bid = blockIdx.x;
  const int rw = bid >> 9;          // /CPR
  const int chunk = bid & (CPR - 1);
  const float* x = row_ptr(rppg, ppg, rw);
  const int lane = threadIdx.x & 63;
  const int wid = threadIdx.x >> 6;
  const int s = chunk * CHUNK + wid * (64 * EPL) + lane * EPL;

  float X[26], w[16];
  window16(x, s, X, w);

  double tsum = 0.0, tpk = 0.0;
  int tn = 0;
#pragma unroll
  for (int t = 0; t < 16; ++t) {
    float v = X[5 + t];
    tsum += (double)v;
    if (v == w[t]) { tpk += (double)v; ++tn; }
  }
#pragma unroll
  for (int off = 32; off > 0; off >>= 1) {
    tsum += __shfl_down(tsum, off);
    tpk  += __shfl_down(tpk, off);
    tn   += __shfl_down(tn, off);
  }

  __shared__ double wsum[4], wpk[4];
  __shared__ int wn[4];
  __shared__ int lastFlag;
  if (lane == 0) { wsum[wid] = tsum; wpk[wid] = tpk; wn[wid] = tn; }
  __syncthreads();
  if (threadIdx.x == 0) {
    psum[bid] = wsum[0] + wsum[1] + wsum[2] + wsum[3];
    ppk[bid]  = wpk[0] + wpk[1] + wpk[2] + wpk[3];
    pnpk[bid] = wn[0] + wn[1] + wn[2] + wn[3];
    __threadfence();                       // release chunk results
    lastFlag = (atomicAdd(counter, 1) == NBLK - 1);
  }
  __syncthreads();
  if (!lastFlag) return;
  __threadfence();                         // acquire all chunk results

  const int t = threadIdx.x;
  for (int r = 0; r < NSER; ++r) {
    double s0 = psum[r * CPR + t] + psum[r * CPR + t + 256];
    double p0 = ppk[r * CPR + t] + ppk[r * CPR + t + 256];
    int n0 = pnpk[r * CPR + t] + pnpk[r * CPR + t + 256];
#pragma unroll
    for (int off = 32; off > 0; off >>= 1) {
      s0 += __shfl_down(s0, off);
      p0 += __shfl_down(p0, off);
      n0 += __shfl_down(n0, off);
    }
    if (lane == 0) { wsum[wid] = s0; wpk[wid] = p0; wn[wid] = n0; }
    __syncthreads();
    if (t == 0) {
      double S = wsum[0] + wsum[1] + wsum[2] + wsum[3];
      double P = wpk[0] + wpk[1] + wpk[2] + wpk[3];
      double Nn = (double)(wn[0] + wn[1] + wn[2] + wn[3]);
      thr[r] = 0.5 * (S / (double)LNUM + P / Nn);
    }
    __syncthreads();
  }
}

// Pass 2: per-chunk ordered gap aggregates; last block combines per row
// (ordered), computes hr per row, and writes the final score.
__global__ __launch_bounds__(TPB) void gap_kernel(
    const float* __restrict__ rppg, const float* __restrict__ ppg,
    const double* __restrict__ thr,
    int* __restrict__ cfirst, int* __restrict__ clast,
    double* __restrict__ csum, int* __restrict__ ccnt,
    const int* __restrict__ fsp, float* __restrict__ out,
    int* __restrict__ counter) {
  const int bid = blockIdx.x;
  const int rw = bid >> 9;
  const int chunk = bid & (CPR - 1);
  const float* x = row_ptr(rppg, ppg, rw);
  const float th = (float)thr[rw];
  const int lane = threadIdx.x & 63;
  const int wid = threadIdx.x >> 6;
  const int s = chunk * CHUNK + wid * (64 * EPL) + lane * EPL;

  float X[26], w[16];
  window16(x, s, X, w);

  Agg a; a.first = -1; a.last = -1; a.c = 0; a.s = 0.0;
#pragma unroll
  for (int t = 0; t < 16; ++t) {
    float v = X[5 + t];
    if (v == w[t] && v > th) {
      int p = s + t;
      if (a.last >= 0) { a.s += 1.0 / (double)(p - a.last); ++a.c; }
      else a.first = p;
      a.last = p;
    }
  }
  // ordered wave tree: lane i's segment is left of lane i+off's
#pragma unroll
  for (int off = 1; off < 64; off <<= 1) {
    Agg b;
    b.first = __shfl_down(a.first, off);
    b.last  = __shfl_down(a.last, off);
    b.c     = __shfl_down(a.c, off);
    b.s     = __shfl_down(a.s, off);
    a = combine(a, b);
  }

  __shared__ Agg waggs[4];
  __shared__ double shr[NSER];
  __shared__ int lastFlag;
  if (lane == 0) waggs[wid] = a;
  __syncthreads();
  if (threadIdx.x == 0) {
    Agg r = waggs[0];
    r = combine(r, waggs[1]);
    r = combine(r, waggs[2]);
    r = combine(r, waggs[3]);
    cfirst[bid] = r.first; clast[bid] = r.last;
    csum[bid] = r.s; ccnt[bid] = r.c;
    __threadfence();
    lastFlag = (atomicAdd(counter, 1) == NBLK - 1);
  }
  __syncthreads();
  if (!lastFlag) return;
  __threadfence();

  const int t = threadIdx.x;
  for (int r = 0; r < NSER; ++r) {
    const int i0 = r * CPR + 2 * t;
    Agg a0; a0.first = cfirst[i0];     a0.last = clast[i0];
    a0.c = ccnt[i0];                   a0.s = csum[i0];
    Agg a1; a1.first = cfirst[i0 + 1]; a1.last = clast[i0 + 1];
    a1.c = ccnt[i0 + 1];               a1.s = csum[i0 + 1];
    a0 = combine(a0, a1);
#pragma unroll
    for (int off = 1; off < 64; off <<= 1) {
      Agg b;
      b.first = __shfl_down(a0.first, off);
      b.last  = __shfl_down(a0.last, off);
      b.c     = __shfl_down(a0.c, off);
      b.s     = __shfl_down(a0.s, off);
      a0 = combine(a0, b);
    }
    if (lane == 0) waggs[wid] = a0;
    __syncthreads();
    if (t == 0) {
      Agg rr = waggs[0];
      rr = combine(rr, waggs[1]);
      rr = combine(rr, waggs[2]);
      rr = combine(rr, waggs[3]);
      shr[r] = 60.0 * (double)fsp[0] * rr.s / (double)rr.c;
    }
    __syncthreads();
  }
  if (t == 0) {
    double acc = 0.0;
    for (int r = 0; r < NROW; ++r)
      acc += fabs(shr[NROW + r] - shr[r]) / shr[NROW + r];
    out[0] = (float)(acc / (double)NROW);
  }
}

}  // namespace

extern "C" void kernel_launch(void* const* d_in, const int* in_sizes, int n_in,
                              void* d_out, int out_size, void* d_ws, size_t ws_size,
                              hipStream_t stream) {
  const float* rppg = (const float*)d_in[0];
  const float* ppg  = (const float*)d_in[1];
  const int* fsp    = (const int*)d_in[2];
  float* out        = (float*)d_out;
  char* ws          = (char*)d_ws;

  // ws layout (all naturally aligned)
  double* psum   = (double*)(ws);            // 5120*8 = 40960
  double* ppk    = (double*)(ws + 40960);    // 40960
  int*    pnpk   = (int*)(ws + 81920);       // 20480
  double* csum   = (double*)(ws + 102400);   // 40960
  int*    cfirst = (int*)(ws + 143360);      // 20480
  int*    clast  = (int*)(ws + 163840);      // 20480
  int*    ccnt   = (int*)(ws + 184320);      // 20480
  double* thr    = (double*)(ws + 204800);   // 80
  int*    counters = (int*)(ws + 204928);    // 8 (two counters)
  // total ~205 KB

  hipMemsetAsync(counters, 0, 2 * sizeof(int), stream);
  stats_kernel<<<NBLK, TPB, 0, stream>>>(rppg, ppg, psum, ppk, pnpk, thr,
                                         counters + 0);
  gap_kernel<<<NBLK, TPB, 0, stream>>>(rppg, ppg, thr, cfirst, clast, csum,
                                       ccnt, fsp, out, counters + 1);
  (void)in_sizes; (void)n_in; (void)out_size; (void)ws_size;
}

// Round 4
// 154.380 us; speedup vs baseline: 2.4907x; 2.4907x over previous
//
#include <hip/hip_runtime.h>
#include <math.h>

namespace {

constexpr int LNUM = 2097152;        // L
constexpr int NROW = 5;              // N
constexpr int NSER = 10;             // rows total (0..4 rppg, 5..9 ppg)
constexpr int TPB = 256;
constexpr int EPL = 16;              // elements per lane (one 64B line)
constexpr int CHUNK = TPB * EPL;     // 4096 per block
constexpr int CPR = LNUM / CHUNK;    // 512 chunks per row
constexpr int NBLK = NSER * CPR;     // 5120

struct Agg { int first; int last; int c; double s; };

__device__ __forceinline__ Agg combine(const Agg& a, const Agg& b) {
  // ordered segment-concat monoid: a LEFT, b RIGHT (non-commutative)
  Agg r;
  r.first = (a.first >= 0) ? a.first : b.first;
  r.last  = (b.last >= 0) ? b.last : a.last;
  r.s = a.s + b.s;
  r.c = a.c + b.c;
  if (a.last >= 0 && b.first >= 0) {
    r.s += 1.0 / (double)(b.first - a.last);
    r.c += 1;
  }
  return r;
}

// Per-lane: 16 contiguous elements at row-relative offset s (s % 16 == 0).
// Own data = one 64B line via 4x dwordx4; halo +-5 via shuffles from
// neighbor lanes; lanes 0/63 patch halo with guarded global loads (-inf pad
// at row edges). Window-11 max via register doubling (m2/m4/m8).
// X[i] = x[s-5+i]  (i=0..25);  w[t] = max over window centered at X[5+t].
__device__ __forceinline__ void window16(const float* __restrict__ x, int s,
                                         float X[26], float w[16]) {
  const float4* q = reinterpret_cast<const float4*>(x + s);
  float4 f0 = q[0], f1 = q[1], f2 = q[2], f3 = q[3];
  X[5] = f0.x;  X[6] = f0.y;  X[7] = f0.z;  X[8] = f0.w;
  X[9] = f1.x;  X[10] = f1.y; X[11] = f1.z; X[12] = f1.w;
  X[13] = f2.x; X[14] = f2.y; X[15] = f2.z; X[16] = f2.w;
  X[17] = f3.x; X[18] = f3.y; X[19] = f3.z; X[20] = f3.w;
#pragma unroll
  for (int j = 0; j < 5; ++j) X[j] = __shfl_up(X[16 + j], 1);      // x[s-5+j]
#pragma unroll
  for (int j = 0; j < 5; ++j) X[21 + j] = __shfl_down(X[5 + j], 1); // x[s+16+j]
  const int lane = threadIdx.x & 63;
  if (lane == 0) {
#pragma unroll
    for (int j = 0; j < 5; ++j) {
      int g = s - 5 + j;
      X[j] = (g >= 0) ? x[g] : -INFINITY;
    }
  }
  if (lane == 63) {
#pragma unroll
    for (int j = 0; j < 5; ++j) {
      int g = s + 16 + j;
      X[21 + j] = (g < LNUM) ? x[g] : -INFINITY;
    }
  }
  float m2[25];
#pragma unroll
  for (int i = 0; i < 25; ++i) m2[i] = fmaxf(X[i], X[i + 1]);
  float m4[23];
#pragma unroll
  for (int i = 0; i < 23; ++i) m4[i] = fmaxf(m2[i], m2[i + 2]);
  float m8[19];
#pragma unroll
  for (int i = 0; i < 19; ++i) m8[i] = fmaxf(m4[i], m4[i + 4]);
#pragma unroll
  for (int t = 0; t < 16; ++t) w[t] = fmaxf(m8[t], m8[t + 3]);  // X[t..t+10]
}

__device__ __forceinline__ const float* row_ptr(const float* rppg,
                                                const float* ppg, int rw) {
  return (rw < NROW) ? rppg + (size_t)rw * LNUM
                     : ppg + (size_t)(rw - NROW) * LNUM;
}

// Pass 1: per-chunk {sum, peak-value-sum, peak-count}. NO atomics.
__global__ __launch_bounds__(TPB) void stats_kernel(
    const float* __restrict__ rppg, const float* __restrict__ ppg,
    double* __restrict__ psum, double* __restrict__ ppk,
    int* __restrict__ pnpk) {
  const int bid = blockIdx.x;
  const int rw = bid >> 9;          // /CPR
  const int chunk = bid & (CPR - 1);
  const float* x = row_ptr(rppg, ppg, rw);
  const int lane = threadIdx.x & 63;
  const int wid = threadIdx.x >> 6;
  const int s = chunk * CHUNK + wid * (64 * EPL) + lane * EPL;

  float X[26], w[16];
  window16(x, s, X, w);

  double tsum = 0.0, tpk = 0.0;
  int tn = 0;
#pragma unroll
  for (int t = 0; t < 16; ++t) {
    float v = X[5 + t];
    tsum += (double)v;
    if (v == w[t]) { tpk += (double)v; ++tn; }
  }
#pragma unroll
  for (int off = 32; off > 0; off >>= 1) {
    tsum += __shfl_down(tsum, off);
    tpk  += __shfl_down(tpk, off);
    tn   += __shfl_down(tn, off);
  }

  __shared__ double wsum[4], wpk[4];
  __shared__ int wn[4];
  if (lane == 0) { wsum[wid] = tsum; wpk[wid] = tpk; wn[wid] = tn; }
  __syncthreads();
  if (threadIdx.x == 0) {
    psum[bid] = wsum[0] + wsum[1] + wsum[2] + wsum[3];
    ppk[bid]  = wpk[0] + wpk[1] + wpk[2] + wpk[3];
    pnpk[bid] = wn[0] + wn[1] + wn[2] + wn[3];
  }
}

// Tiny: per-row raw-domain threshold from chunk partials.
// x_norm > mean_pk_norm/2  <=>  x > (mu + mean_pk_raw)/2  (affine, sd cancels)
__global__ __launch_bounds__(TPB) void thresh_kernel(
    const double* __restrict__ psum, const double* __restrict__ ppk,
    const int* __restrict__ pnpk, double* __restrict__ thr) {
  const int r = blockIdx.x;  // 0..9
  const int t = threadIdx.x;
  const int lane = t & 63;
  const int wid = t >> 6;
  double s0 = psum[r * CPR + t] + psum[r * CPR + t + 256];
  double p0 = ppk[r * CPR + t] + ppk[r * CPR + t + 256];
  int n0 = pnpk[r * CPR + t] + pnpk[r * CPR + t + 256];
#pragma unroll
  for (int off = 32; off > 0; off >>= 1) {
    s0 += __shfl_down(s0, off);
    p0 += __shfl_down(p0, off);
    n0 += __shfl_down(n0, off);
  }
  __shared__ double ws[4], wp[4];
  __shared__ int wn[4];
  if (lane == 0) { ws[wid] = s0; wp[wid] = p0; wn[wid] = n0; }
  __syncthreads();
  if (t == 0) {
    double S = ws[0] + ws[1] + ws[2] + ws[3];
    double P = wp[0] + wp[1] + wp[2] + wp[3];
    double Nn = (double)(wn[0] + wn[1] + wn[2] + wn[3]);
    thr[r] = 0.5 * (S / (double)LNUM + P / Nn);
  }
}

// Pass 2: per-chunk ordered gap aggregates. NO atomics.
__global__ __launch_bounds__(TPB) void gap_kernel(
    const float* __restrict__ rppg, const float* __restrict__ ppg,
    const double* __restrict__ thr,
    int* __restrict__ cfirst, int* __restrict__ clast,
    double* __restrict__ csum, int* __restrict__ ccnt) {
  const int bid = blockIdx.x;
  const int rw = bid >> 9;
  const int chunk = bid & (CPR - 1);
  const float* x = row_ptr(rppg, ppg, rw);
  const float th = (float)thr[rw];
  const int lane = threadIdx.x & 63;
  const int wid = threadIdx.x >> 6;
  const int s = chunk * CHUNK + wid * (64 * EPL) + lane * EPL;

  float X[26], w[16];
  window16(x, s, X, w);

  Agg a; a.first = -1; a.last = -1; a.c = 0; a.s = 0.0;
#pragma unroll
  for (int t = 0; t < 16; ++t) {
    float v = X[5 + t];
    if (v == w[t] && v > th) {
      int p = s + t;
      if (a.last >= 0) { a.s += 1.0 / (double)(p - a.last); ++a.c; }
      else a.first = p;
      a.last = p;
    }
  }
  // ordered wave tree: lane i's segment is immediately left of lane i+off's
#pragma unroll
  for (int off = 1; off < 64; off <<= 1) {
    Agg b;
    b.first = __shfl_down(a.first, off);
    b.last  = __shfl_down(a.last, off);
    b.c     = __shfl_down(a.c, off);
    b.s     = __shfl_down(a.s, off);
    a = combine(a, b);
  }

  __shared__ Agg waggs[4];
  if (lane == 0) waggs[wid] = a;
  __syncthreads();
  if (threadIdx.x == 0) {
    Agg r = waggs[0];
    r = combine(r, waggs[1]);
    r = combine(r, waggs[2]);
    r = combine(r, waggs[3]);
    cfirst[bid] = r.first; clast[bid] = r.last;
    csum[bid] = r.s; ccnt[bid] = r.c;
  }
}

// Final: one block; per row combine the 512 chunk Aggs in order -> hr,
// then the score. Thread t covers chunks {2t, 2t+1} (segment order = lane
// order within each wave; waves combined in order afterwards).
__global__ __launch_bounds__(TPB) void final_kernel(
    const int* __restrict__ cfirst, const int* __restrict__ clast,
    const double* __restrict__ csum, const int* __restrict__ ccnt,
    const int* __restrict__ fsp, float* __restrict__ out) {
  __shared__ Agg waggs[4];
  __shared__ double shr[NSER];
  const int t = threadIdx.x;
  const int lane = t & 63;
  const int wid = t >> 6;
  for (int r = 0; r < NSER; ++r) {
    const int i0 = r * CPR + 2 * t;
    Agg a0; a0.first = cfirst[i0];     a0.last = clast[i0];
    a0.c = ccnt[i0];                   a0.s = csum[i0];
    Agg a1; a1.first = cfirst[i0 + 1]; a1.last = clast[i0 + 1];
    a1.c = ccnt[i0 + 1];               a1.s = csum[i0 + 1];
    a0 = combine(a0, a1);
#pragma unroll
    for (int off = 1; off < 64; off <<= 1) {
      Agg b;
      b.first = __shfl_down(a0.first, off);
      b.last  = __shfl_down(a0.last, off);
      b.c     = __shfl_down(a0.c, off);
      b.s     = __shfl_down(a0.s, off);
      a0 = combine(a0, b);
    }
    if (lane == 0) waggs[wid] = a0;
    __syncthreads();
    if (t == 0) {
      Agg rr = waggs[0];
      rr = combine(rr, waggs[1]);
      rr = combine(rr, waggs[2]);
      rr = combine(rr, waggs[3]);
      shr[r] = 60.0 * (double)fsp[0] * rr.s / (double)rr.c;
    }
    __syncthreads();
  }
  if (t == 0) {
    double acc = 0.0;
    for (int r = 0; r < NROW; ++r)
      acc += fabs(shr[NROW + r] - shr[r]) / shr[NROW + r];
    out[0] = (float)(acc / (double)NROW);
  }
}

}  // namespace

extern "C" void kernel_launch(void* const* d_in, const int* in_sizes, int n_in,
                              void* d_out, int out_size, void* d_ws, size_t ws_size,
                              hipStream_t stream) {
  const float* rppg = (const float*)d_in[0];
  const float* ppg  = (const float*)d_in[1];
  const int* fsp    = (const int*)d_in[2];
  float* out        = (float*)d_out;
  char* ws          = (char*)d_ws;

  // ws layout (all naturally aligned)
  double* psum   = (double*)(ws);            // 5120*8 = 40960
  double* ppk    = (double*)(ws + 40960);    // 40960
  int*    pnpk   = (int*)(ws + 81920);       // 20480
  double* csum   = (double*)(ws + 102400);   // 40960
  int*    cfirst = (int*)(ws + 143360);      // 20480
  int*    clast  = (int*)(ws + 163840);      // 20480
  int*    ccnt   = (int*)(ws + 184320);      // 20480
  double* thr    = (double*)(ws + 204800);   // 80
  // total ~205 KB

  stats_kernel<<<NBLK, TPB, 0, stream>>>(rppg, ppg, psum, ppk, pnpk);
  thresh_kernel<<<NSER, TPB, 0, stream>>>(psum, ppk, pnpk, thr);
  gap_kernel<<<NBLK, TPB, 0, stream>>>(rppg, ppg, thr, cfirst, clast, csum, ccnt);
  final_kernel<<<1, TPB, 0, stream>>>(cfirst, clast, csum, ccnt, fsp, out);
  (void)in_sizes; (void)n_in; (void)out_size; (void)ws_size;
}